// Round 3
// baseline (517.571 us; speedup 1.0000x reference)
//
#include <hip/hip_runtime.h>
#include <math.h>

#define EPSV 1e-5f
#define B 8
#define C 1024
#define C2 512
#define RK 73
#define H 28
#define HW 784      // 28*28
#define QW 3136     // 56*56

typedef __attribute__((ext_vector_type(8))) short bf16x8;
typedef __attribute__((ext_vector_type(4))) float f32x4;

__device__ __forceinline__ unsigned short f2bf(float f) {
    unsigned u = __float_as_uint(f);
    unsigned r = (u + 0x7fffu + ((u >> 16) & 1u)) >> 16;
    return (unsigned short)r;
}

// ---------- kernel 1: global average pool over y -> s0 (B*C2) ----------
__global__ void gap_kernel(const float* __restrict__ y, float* __restrict__ s0) {
    int bc = blockIdx.x;
    const float* p = y + (size_t)bc * QW;
    float sum = 0.f;
    for (int i = threadIdx.x; i < QW; i += 256) sum += p[i];
    for (int off = 32; off > 0; off >>= 1) sum += __shfl_down(sum, off, 64);
    __shared__ float red[4];
    if ((threadIdx.x & 63) == 0) red[threadIdx.x >> 6] = sum;
    __syncthreads();
    if (threadIdx.x == 0)
        s0[bc] = (red[0] + red[1] + red[2] + red[3]) * (1.0f / QW);
}

// ---------- kernel 2: SE FC layers ----------
__global__ void se_fc_kernel(const float* __restrict__ s0,
                             const float* __restrict__ fc1_w,
                             const float* __restrict__ fc2_w,
                             float* __restrict__ att) {
    int b = blockIdx.x;
    __shared__ float sv[C2];
    __shared__ float hv[RK];
    for (int i = threadIdx.x; i < C2; i += 256) sv[i] = s0[b * C2 + i];
    __syncthreads();
    if (threadIdx.x < RK) {
        float acc = 0.f;
        const float* wr = fc1_w + threadIdx.x * C2;
        for (int k = 0; k < C2; ++k) acc += wr[k] * sv[k];
        hv[threadIdx.x] = fmaxf(acc, 0.f);
    }
    __syncthreads();
    for (int o = threadIdx.x; o < C2; o += 256) {
        float acc = 0.f;
        const float* wr = fc2_w + o * RK;
        for (int j = 0; j < RK; ++j) acc += wr[j] * hv[j];
        att[b * C2 + o] = 1.f / (1.f + expf(-acc));
    }
}

// ---------- kernel 3: depthwise 3x3 conv + row-centered cov ----------
__global__ void dwcov_kernel(const float* __restrict__ x,
                             const float* __restrict__ dw_w,
                             const float* __restrict__ dw_b,
                             float* __restrict__ cov) {
    int bc = blockIdx.x;
    int c = bc & (C - 1);
    __shared__ float xs[HW];
    __shared__ float x1[HW];
    __shared__ float rm[H];
    const float* px = x + (size_t)bc * HW;
    for (int i = threadIdx.x; i < HW; i += 256) xs[i] = px[i];
    float wk[9];
#pragma unroll
    for (int j = 0; j < 9; ++j) wk[j] = dw_w[c * 9 + j];
    float bias = dw_b[c];
    __syncthreads();
    for (int p = threadIdx.x; p < HW; p += 256) {
        int h = p / 28, w = p - h * 28;
        float acc = bias;
#pragma unroll
        for (int dh = 0; dh < 3; ++dh) {
            int hh = h + dh - 1;
            if (hh < 0 || hh >= H) continue;
#pragma unroll
            for (int dw = 0; dw < 3; ++dw) {
                int ww = w + dw - 1;
                if (ww < 0 || ww >= 28) continue;
                acc += xs[hh * 28 + ww] * wk[dh * 3 + dw];
            }
        }
        x1[p] = acc;
    }
    __syncthreads();
    if (threadIdx.x < H) {
        float s = 0.f;
        for (int w = 0; w < 28; ++w) s += x1[threadIdx.x * 28 + w];
        rm[threadIdx.x] = s * (1.f / 28.f);
    }
    __syncthreads();
    float* pc = cov + (size_t)bc * HW;
    for (int p = threadIdx.x; p < HW; p += 256) {
        int h = p / 28, g = p - h * 28;
        float mh = rm[h], mg = rm[g];
        float acc = 0.f;
        for (int w = 0; w < 28; ++w)
            acc += (x1[h * 28 + w] - mh) * (x1[g * 28 + w] - mg);
        pc[p] = acc * (1.f / 27.f);
    }
}

// ---------- prep: pack weights bf16; fold att into W1y; fold bias+bn ----------
__global__ void pack_kernel(const float* __restrict__ conv_w, const float* __restrict__ conv_b,
                            const float* __restrict__ conv1_w, const float* __restrict__ conv1_b,
                            const float* __restrict__ bn_g, const float* __restrict__ bn_b,
                            const float* __restrict__ bn_m, const float* __restrict__ bn_v,
                            const float* __restrict__ att,
                            unsigned short* __restrict__ w0b, unsigned short* __restrict__ w1p,
                            unsigned short* __restrict__ w1y,
                            float* __restrict__ sA, float* __restrict__ sB0, float* __restrict__ sB1) {
    int o = blockIdx.x;
    int t = threadIdx.x;
    for (int i = t; i < C; i += 256) w0b[(size_t)o * C + i] = f2bf(conv_w[(size_t)o * C + i]);
    for (int i = t; i < 1536; i += 256) w1p[(size_t)o * 1536 + i] = f2bf(conv1_w[(size_t)o * 2048 + 512 + i]);
#pragma unroll
    for (int b = 0; b < B; ++b)
        for (int c = t; c < C2; c += 256)
            w1y[((size_t)b * C2 + o) * C2 + c] = f2bf(conv1_w[(size_t)o * 2048 + c] * att[b * C2 + c]);
    if (t == 0) {
        float sc = rsqrtf(bn_v[o] + EPSV) * bn_g[o];
        float bi = bn_b[o] - bn_m[o] * sc;
        sA[o] = sc;
        sB0[o] = conv_b[o] * sc + bi;
        sB1[o] = conv1_b[o] * sc + bi;
    }
}

// ---------- MFMA GEMM, o-tile 128 x q-tile 64, BK=32 ----------
// MODE 0: B=cov f32 (K=1024,N=784), epi sigmoid*bn -> x2s
// MODE 1: B=[x2s|x] f32 (K=1536,N=784), epi raw -> P
// MODE 2: B=y f32, A=W1y[b] (K=512,N=3136), epi (acc+up(P))*bn relu -> out
template<int MODE, int K, int NQ>
__global__ __launch_bounds__(256)
void mfma_gemm(const unsigned short* __restrict__ wpk,
               const float* __restrict__ b0, const float* __restrict__ b1,
               const float* __restrict__ sA, const float* __restrict__ sB,
               const float* __restrict__ Pin,
               float* __restrict__ outp) {
    int b = blockIdx.z;
    int o0 = blockIdx.y * 128;
    int q0 = blockIdx.x * 64;
    __shared__ __align__(16) unsigned short Wt[128 * 40];
    __shared__ __align__(16) unsigned short At[64 * 40];
    int tid = threadIdx.x;
    int lane = tid & 63, wv = tid >> 6;
    int ln = lane & 15, quad = lane >> 4;
    int o_w = (wv >> 1) * 64, q_w = (wv & 1) * 32;
    int sr = tid >> 1, skh = (tid & 1) * 16;   // W staging
    int gq = tid & 63, gk8 = tid >> 6;         // B staging
    int qg = q0 + gq;
    const unsigned short* wp = (MODE == 2) ? wpk + (size_t)b * C2 * C2 : wpk;

    f32x4 acc[4][2] = {};
    for (int k0 = 0; k0 < K; k0 += 32) {
        __syncthreads();
        {   // stage W tile [128][32] pitch 40
            const unsigned short* src = wp + (size_t)(o0 + sr) * K + k0 + skh;
            float4 va = *(const float4*)src;
            float4 vb = *(const float4*)(src + 8);
            *(float4*)&Wt[sr * 40 + skh] = va;
            *(float4*)&Wt[sr * 40 + skh + 8] = vb;
        }
        {   // stage B tile [64 q][32 k] pitch 40: strided f32 loads + cvt
            unsigned short pk[8];
            int ch = k0 + gk8 * 8;
            const float* src;
            size_t stride;
            if (MODE == 0) {
                src = b0 + ((size_t)b * C + ch) * HW + qg; stride = HW;
            } else if (MODE == 1) {
                if (ch < C2) src = b0 + ((size_t)b * C2 + ch) * HW + qg;
                else         src = b1 + ((size_t)b * C + (ch - C2)) * HW + qg;
                stride = HW;
            } else {
                src = b0 + ((size_t)b * C2 + ch) * QW + qg; stride = QW;
            }
            bool inb = (NQ % 64 == 0) || (qg < NQ);
#pragma unroll
            for (int j = 0; j < 8; ++j)
                pk[j] = inb ? f2bf(src[(size_t)j * stride]) : (unsigned short)0;
            *(float4*)&At[gq * 40 + gk8 * 8] = *(float4*)pk;
        }
        __syncthreads();
        bf16x8 af[4], bfr[2];
#pragma unroll
        for (int mt = 0; mt < 4; ++mt)
            af[mt] = *(const bf16x8*)&Wt[(o_w + mt * 16 + ln) * 40 + quad * 8];
#pragma unroll
        for (int nt = 0; nt < 2; ++nt)
            bfr[nt] = *(const bf16x8*)&At[(q_w + nt * 16 + ln) * 40 + quad * 8];
#pragma unroll
        for (int mt = 0; mt < 4; ++mt)
#pragma unroll
            for (int nt = 0; nt < 2; ++nt)
                acc[mt][nt] = __builtin_amdgcn_mfma_f32_16x16x32_bf16(af[mt], bfr[nt], acc[mt][nt], 0, 0, 0);
    }
    // epilogue; D: row = quad*4+reg, col = ln
    if (MODE == 2) {
#pragma unroll
        for (int nt = 0; nt < 2; ++nt) {
            int q = q0 + q_w + nt * 16 + ln;
            int hq = q / 56, wq = q - hq * 56;
            int hm = hq >> 1, wm = wq >> 1;
            int hn = (hq & 1) ? min(hm + 1, 27) : max(hm - 1, 0);
            int wn = (wq & 1) ? min(wm + 1, 27) : max(wm - 1, 0);
            int i00 = hm * 28 + wm, i01 = hm * 28 + wn, i10 = hn * 28 + wm, i11 = hn * 28 + wn;
#pragma unroll
            for (int mt = 0; mt < 4; ++mt)
#pragma unroll
                for (int reg = 0; reg < 4; ++reg) {
                    int o = o0 + o_w + mt * 16 + quad * 4 + reg;
                    const float* Po = Pin + ((size_t)b * C2 + o) * HW;
                    float up = 0.5625f * Po[i00] + 0.1875f * (Po[i01] + Po[i10]) + 0.0625f * Po[i11];
                    float v = (acc[mt][nt][reg] + up) * sA[o] + sB[o];
                    outp[((size_t)b * C2 + o) * QW + q] = fmaxf(v, 0.f);
                }
        }
    } else {
#pragma unroll
        for (int mt = 0; mt < 4; ++mt)
#pragma unroll
            for (int reg = 0; reg < 4; ++reg) {
                int o = o0 + o_w + mt * 16 + quad * 4 + reg;
                float sc, sb;
                if (MODE == 0) { sc = sA[o]; sb = sB[o]; }
#pragma unroll
                for (int nt = 0; nt < 2; ++nt) {
                    int q = q0 + q_w + nt * 16 + ln;
                    if (q < NQ) {
                        if (MODE == 0) {
                            float v = acc[mt][nt][reg] * sc + sb;
                            outp[((size_t)b * C2 + o) * HW + q] = 1.f / (1.f + expf(-v));
                        } else {
                            outp[((size_t)b * C2 + o) * HW + q] = acc[mt][nt][reg];
                        }
                    }
                }
            }
    }
}

extern "C" void kernel_launch(void* const* d_in, const int* in_sizes, int n_in,
                              void* d_out, int out_size, void* d_ws, size_t ws_size,
                              hipStream_t stream) {
    const float* y       = (const float*)d_in[0];
    const float* x       = (const float*)d_in[1];
    const float* fc1_w   = (const float*)d_in[2];
    const float* fc2_w   = (const float*)d_in[3];
    const float* conv_w  = (const float*)d_in[4];
    const float* conv_b  = (const float*)d_in[5];
    const float* conv1_w = (const float*)d_in[6];
    const float* conv1_b = (const float*)d_in[7];
    const float* bn_g    = (const float*)d_in[8];
    const float* bn_b    = (const float*)d_in[9];
    const float* bn_m    = (const float*)d_in[10];
    const float* bn_v    = (const float*)d_in[11];
    const float* dw_w    = (const float*)d_in[12];
    const float* dw_b    = (const float*)d_in[13];
    float* out = (float*)d_out;

    float* ws  = (float*)d_ws;
    float* s0  = ws;                               // 4096
    float* att = s0 + 4096;                        // 4096
    float* sA  = att + 4096;                       // 512
    float* sB0 = sA + 512;                         // 512
    float* sB1 = sB0 + 512;                        // 512
    float* cov = ws + 16384;                       // 8*1024*784 f32 (reused as P)
    float* x2s = cov + (size_t)B * C * HW;         // 8*512*784 f32
    unsigned short* w0b = (unsigned short*)(x2s + (size_t)B * C2 * HW); // 512*1024
    unsigned short* w1p = w0b + (size_t)C2 * C;    // 512*1536
    unsigned short* w1y = w1p + (size_t)C2 * 1536; // 8*512*512
    float* P = cov;                                // reuse: cov dead after MODE0
    // total ws use ~45.4 MB

    gap_kernel<<<B * C2, 256, 0, stream>>>(y, s0);
    se_fc_kernel<<<B, 256, 0, stream>>>(s0, fc1_w, fc2_w, att);
    pack_kernel<<<C2, 256, 0, stream>>>(conv_w, conv_b, conv1_w, conv1_b,
                                        bn_g, bn_b, bn_m, bn_v, att,
                                        w0b, w1p, w1y, sA, sB0, sB1);
    dwcov_kernel<<<B * C, 256, 0, stream>>>(x, dw_w, dw_b, cov);
    dim3 g0(13, 4, 8);
    mfma_gemm<0, 1024, 784><<<g0, 256, 0, stream>>>(w0b, cov, nullptr, sA, sB0, nullptr, x2s);
    dim3 g1(13, 4, 8);
    mfma_gemm<1, 1536, 784><<<g1, 256, 0, stream>>>(w1p, x2s, x, sA, sB0, nullptr, P);
    dim3 g2(49, 4, 8);
    mfma_gemm<2, 512, 3136><<<g2, 256, 0, stream>>>(w1y, y, nullptr, sA, sB1, P, out);
}

// Round 4
// 421.207 us; speedup vs baseline: 1.2288x; 1.2288x over previous
//
#include <hip/hip_runtime.h>
#include <math.h>

#define EPSV 1e-5f
#define B 8
#define C 1024
#define C2 512
#define RK 73
#define H 28
#define HW 784      // 28*28
#define QW 3136     // 56*56

typedef __attribute__((ext_vector_type(8))) short bf16x8;
typedef __attribute__((ext_vector_type(4))) float f32x4;

__device__ __forceinline__ unsigned short f2bf(float f) {
    unsigned u = __float_as_uint(f);
    unsigned r = (u + 0x7fffu + ((u >> 16) & 1u)) >> 16;
    return (unsigned short)r;
}

// ---------- kernel 1: global average pool over y -> s0 (B*C2) ----------
__global__ void gap_kernel(const float* __restrict__ y, float* __restrict__ s0) {
    int bc = blockIdx.x;
    const float* p = y + (size_t)bc * QW;
    float sum = 0.f;
    for (int i = threadIdx.x; i < QW; i += 256) sum += p[i];
    for (int off = 32; off > 0; off >>= 1) sum += __shfl_down(sum, off, 64);
    __shared__ float red[4];
    if ((threadIdx.x & 63) == 0) red[threadIdx.x >> 6] = sum;
    __syncthreads();
    if (threadIdx.x == 0)
        s0[bc] = (red[0] + red[1] + red[2] + red[3]) * (1.0f / QW);
}

// ---------- kernel 2: SE FC layers ----------
__global__ void se_fc_kernel(const float* __restrict__ s0,
                             const float* __restrict__ fc1_w,
                             const float* __restrict__ fc2_w,
                             float* __restrict__ att) {
    int b = blockIdx.x;
    __shared__ float sv[C2];
    __shared__ float hv[RK];
    for (int i = threadIdx.x; i < C2; i += 256) sv[i] = s0[b * C2 + i];
    __syncthreads();
    if (threadIdx.x < RK) {
        float acc = 0.f;
        const float* wr = fc1_w + threadIdx.x * C2;
        for (int k = 0; k < C2; ++k) acc += wr[k] * sv[k];
        hv[threadIdx.x] = fmaxf(acc, 0.f);
    }
    __syncthreads();
    for (int o = threadIdx.x; o < C2; o += 256) {
        float acc = 0.f;
        const float* wr = fc2_w + o * RK;
        for (int j = 0; j < RK; ++j) acc += wr[j] * hv[j];
        att[b * C2 + o] = 1.f / (1.f + expf(-acc));
    }
}

// ---------- kernel 3: depthwise 3x3 conv + row-centered cov ----------
__global__ void dwcov_kernel(const float* __restrict__ x,
                             const float* __restrict__ dw_w,
                             const float* __restrict__ dw_b,
                             float* __restrict__ cov) {
    int bc = blockIdx.x;
    int c = bc & (C - 1);
    __shared__ float xs[HW];
    __shared__ float x1[HW];
    __shared__ float rm[H];
    const float* px = x + (size_t)bc * HW;
    for (int i = threadIdx.x; i < HW; i += 256) xs[i] = px[i];
    float wk[9];
#pragma unroll
    for (int j = 0; j < 9; ++j) wk[j] = dw_w[c * 9 + j];
    float bias = dw_b[c];
    __syncthreads();
    for (int p = threadIdx.x; p < HW; p += 256) {
        int h = p / 28, w = p - h * 28;
        float acc = bias;
#pragma unroll
        for (int dh = 0; dh < 3; ++dh) {
            int hh = h + dh - 1;
            if (hh < 0 || hh >= H) continue;
#pragma unroll
            for (int dw = 0; dw < 3; ++dw) {
                int ww = w + dw - 1;
                if (ww < 0 || ww >= 28) continue;
                acc += xs[hh * 28 + ww] * wk[dh * 3 + dw];
            }
        }
        x1[p] = acc;
    }
    __syncthreads();
    if (threadIdx.x < H) {
        float s = 0.f;
        for (int w = 0; w < 28; ++w) s += x1[threadIdx.x * 28 + w];
        rm[threadIdx.x] = s * (1.f / 28.f);
    }
    __syncthreads();
    float* pc = cov + (size_t)bc * HW;
    for (int p = threadIdx.x; p < HW; p += 256) {
        int h = p / 28, g = p - h * 28;
        float mh = rm[h], mg = rm[g];
        float acc = 0.f;
        for (int w = 0; w < 28; ++w)
            acc += (x1[h * 28 + w] - mh) * (x1[g * 28 + w] - mg);
        pc[p] = acc * (1.f / 27.f);
    }
}

// ---------- prep: pack weights bf16; fold att into W1y; fold bias+bn ----------
__global__ void pack_kernel(const float* __restrict__ conv_w, const float* __restrict__ conv_b,
                            const float* __restrict__ conv1_w, const float* __restrict__ conv1_b,
                            const float* __restrict__ bn_g, const float* __restrict__ bn_b,
                            const float* __restrict__ bn_m, const float* __restrict__ bn_v,
                            const float* __restrict__ att,
                            unsigned short* __restrict__ w0b, unsigned short* __restrict__ w1p,
                            unsigned short* __restrict__ w1y,
                            float* __restrict__ sA, float* __restrict__ sB0, float* __restrict__ sB1) {
    int o = blockIdx.x;
    int t = threadIdx.x;
    for (int i = t; i < C; i += 256) w0b[(size_t)o * C + i] = f2bf(conv_w[(size_t)o * C + i]);
    for (int i = t; i < 1536; i += 256) w1p[(size_t)o * 1536 + i] = f2bf(conv1_w[(size_t)o * 2048 + 512 + i]);
#pragma unroll
    for (int b = 0; b < B; ++b)
        for (int c = t; c < C2; c += 256)
            w1y[((size_t)b * C2 + o) * C2 + c] = f2bf(conv1_w[(size_t)o * 2048 + c] * att[b * C2 + c]);
    if (t == 0) {
        float sc = rsqrtf(bn_v[o] + EPSV) * bn_g[o];
        float bi = bn_b[o] - bn_m[o] * sc;
        sA[o] = sc;
        sB0[o] = conv_b[o] * sc + bi;
        sB1[o] = conv1_b[o] * sc + bi;
    }
}

// ---------- MFMA GEMM, 64o x 64q tiles, BK=32, double-buffered LDS ----------
// MODE 0: B=cov f32 (K=1024, N=B*784), epi sigmoid*bn -> x2s
// MODE 1: B=[x2s|x] f32 (K=1536, N=B*784), epi raw -> P
// MODE 2: B=y f32, A=W1y[b] (K=512, N=3136, z=b), epi (acc+up(P))*bn relu -> out
template<int MODE, int K>
__global__ __launch_bounds__(256)
void mfma_gemm(const unsigned short* __restrict__ wpk,
               const float* __restrict__ b0, const float* __restrict__ b1,
               const float* __restrict__ sA, const float* __restrict__ sB,
               float* __restrict__ outp) {
    constexpr int NIT = K / 32;
    constexpr int BSTRIDE = (MODE == 2) ? QW : HW;
    int bx = blockIdx.x;
    int o0 = (bx & 7) * 64;      // o-fastest swizzle for B-slice L2 reuse
    int q0 = (bx >> 3) * 64;
    int b = blockIdx.z;
    union SMem {
        struct { unsigned short Wt[2][64 * 40]; unsigned short At[2][64 * 40]; } s;
        float pt[64 * 84];       // MODE2 epilogue P tile (3 rows x 28 per o)
    };
    __shared__ SMem sm;
    int tid = threadIdx.x;
    int lane = tid & 63, wv = tid >> 6;
    int ln = lane & 15, quad = lane >> 4;
    int o_w = (wv >> 1) * 32, q_w = (wv & 1) * 32;
    int swr = tid >> 2, swk = (tid & 3) * 8;   // W staging: row, k-off
    int gq = tid & 63, gk8 = tid >> 6;         // B staging: q, k-octet
    int qg = q0 + gq;
    int bq = 0, pp = qg;
    if (MODE < 2) { bq = qg / HW; pp = qg - bq * HW; }
    const unsigned short* wp = (MODE == 2) ? wpk + (size_t)b * C2 * C2 : wpk;
    const unsigned short* wsrc = wp + (size_t)(o0 + swr) * K + swk;

    auto bbase = [&](int k0) -> const float* {
        int ch = k0 + gk8 * 8;
        if (MODE == 0) return b0 + ((size_t)bq * C + ch) * HW + pp;
        else if (MODE == 1) {
            if (ch < C2) return b0 + ((size_t)bq * C2 + ch) * HW + pp;
            else         return b1 + ((size_t)bq * C + (ch - C2)) * HW + pp;
        } else return b0 + ((size_t)b * C2 + ch) * QW + qg;
    };

    // prologue: chunk 0 -> LDS[0]
    {
        float4 wreg = *(const float4*)wsrc;
        float brg[8];
        const float* s = bbase(0);
#pragma unroll
        for (int j = 0; j < 8; ++j) brg[j] = s[(size_t)j * BSTRIDE];
        *(float4*)&sm.s.Wt[0][swr * 40 + swk] = wreg;
        unsigned short pk[8];
#pragma unroll
        for (int j = 0; j < 8; ++j) pk[j] = f2bf(brg[j]);
        *(float4*)&sm.s.At[0][gq * 40 + gk8 * 8] = *(float4*)pk;
    }
    __syncthreads();

    f32x4 acc[2][2] = {};
    for (int i = 0; i < NIT; ++i) {
        int cur = i & 1;
        float4 wnext;
        float bnext[8];
        if (i + 1 < NIT) {          // issue next chunk's global loads early
            wnext = *(const float4*)(wsrc + (i + 1) * 32);
            const float* s = bbase((i + 1) * 32);
#pragma unroll
            for (int j = 0; j < 8; ++j) bnext[j] = s[(size_t)j * BSTRIDE];
        }
        bf16x8 af[2], bfr[2];
#pragma unroll
        for (int mt = 0; mt < 2; ++mt)
            af[mt] = *(const bf16x8*)&sm.s.Wt[cur][(o_w + mt * 16 + ln) * 40 + quad * 8];
#pragma unroll
        for (int nt = 0; nt < 2; ++nt)
            bfr[nt] = *(const bf16x8*)&sm.s.At[cur][(q_w + nt * 16 + ln) * 40 + quad * 8];
#pragma unroll
        for (int mt = 0; mt < 2; ++mt)
#pragma unroll
            for (int nt = 0; nt < 2; ++nt)
                acc[mt][nt] = __builtin_amdgcn_mfma_f32_16x16x32_bf16(af[mt], bfr[nt], acc[mt][nt], 0, 0, 0);
        if (i + 1 < NIT) {
            int nxt = 1 - cur;
            *(float4*)&sm.s.Wt[nxt][swr * 40 + swk] = wnext;
            unsigned short pk[8];
#pragma unroll
            for (int j = 0; j < 8; ++j) pk[j] = f2bf(bnext[j]);
            *(float4*)&sm.s.At[nxt][gq * 40 + gk8 * 8] = *(float4*)pk;
            __syncthreads();
        }
    }

    // ---- epilogue; D: row = quad*4+reg, col = ln ----
    if (MODE == 2) {
        __syncthreads();
        int h0 = q0 / 56;
        int hmin = (h0 & 1) ? (h0 >> 1) : max(0, (h0 >> 1) - 1);
        for (int e = tid; e < 64 * 84; e += 256) {
            int o_l = e / 84, rem = e - o_l * 84;
            int s = rem / 28, w = rem - s * 28;
            int row = min(hmin + s, 27);
            sm.pt[e] = b1[((size_t)b * C2 + o0 + o_l) * HW + row * 28 + w];
        }
        __syncthreads();
#pragma unroll
        for (int nt = 0; nt < 2; ++nt) {
            int q = q0 + q_w + nt * 16 + ln;
            int hq = q / 56, wq = q - hq * 56;
            int hm = hq >> 1, wm = wq >> 1;
            int hn = (hq & 1) ? min(hm + 1, 27) : max(hm - 1, 0);
            int wn = (wq & 1) ? min(wm + 1, 27) : max(wm - 1, 0);
            int rm_ = (hm - hmin) * 28, rn_ = (hn - hmin) * 28;
#pragma unroll
            for (int mt = 0; mt < 2; ++mt)
#pragma unroll
                for (int reg = 0; reg < 4; ++reg) {
                    int ol = o_w + mt * 16 + quad * 4 + reg;
                    int o = o0 + ol;
                    const float* Pt = &sm.pt[ol * 84];
                    float up = 0.5625f * Pt[rm_ + wm] + 0.1875f * (Pt[rm_ + wn] + Pt[rn_ + wm])
                             + 0.0625f * Pt[rn_ + wn];
                    float v = (acc[mt][nt][reg] + up) * sA[o] + sB[o];
                    outp[((size_t)b * C2 + o) * QW + q] = fmaxf(v, 0.f);
                }
        }
    } else {
#pragma unroll
        for (int nt = 0; nt < 2; ++nt) {
            int qe = q0 + q_w + nt * 16 + ln;
            int be = qe / HW, pe = qe - be * HW;
#pragma unroll
            for (int mt = 0; mt < 2; ++mt)
#pragma unroll
                for (int reg = 0; reg < 4; ++reg) {
                    int o = o0 + o_w + mt * 16 + quad * 4 + reg;
                    float v = acc[mt][nt][reg];
                    if (MODE == 0) {
                        v = v * sA[o] + sB[o];
                        outp[((size_t)be * C2 + o) * HW + pe] = 1.f / (1.f + expf(-v));
                    } else {
                        outp[((size_t)be * C2 + o) * HW + pe] = v;
                    }
                }
        }
    }
}

extern "C" void kernel_launch(void* const* d_in, const int* in_sizes, int n_in,
                              void* d_out, int out_size, void* d_ws, size_t ws_size,
                              hipStream_t stream) {
    const float* y       = (const float*)d_in[0];
    const float* x       = (const float*)d_in[1];
    const float* fc1_w   = (const float*)d_in[2];
    const float* fc2_w   = (const float*)d_in[3];
    const float* conv_w  = (const float*)d_in[4];
    const float* conv_b  = (const float*)d_in[5];
    const float* conv1_w = (const float*)d_in[6];
    const float* conv1_b = (const float*)d_in[7];
    const float* bn_g    = (const float*)d_in[8];
    const float* bn_b    = (const float*)d_in[9];
    const float* bn_m    = (const float*)d_in[10];
    const float* bn_v    = (const float*)d_in[11];
    const float* dw_w    = (const float*)d_in[12];
    const float* dw_b    = (const float*)d_in[13];
    float* out = (float*)d_out;

    float* ws  = (float*)d_ws;
    float* s0  = ws;                               // 4096
    float* att = s0 + 4096;                        // 4096
    float* sA  = att + 4096;                       // 512
    float* sB0 = sA + 512;                         // 512
    float* sB1 = sB0 + 512;                        // 512
    float* cov = ws + 16384;                       // 8*1024*784 f32 (reused as P)
    float* x2s = cov + (size_t)B * C * HW;         // 8*512*784 f32
    unsigned short* w0b = (unsigned short*)(x2s + (size_t)B * C2 * HW); // 512*1024
    unsigned short* w1p = w0b + (size_t)C2 * C;    // 512*1536
    unsigned short* w1y = w1p + (size_t)C2 * 1536; // 8*512*512
    float* P = cov;                                // reuse: cov dead after MODE0
    // total ws use ~45.4 MB

    gap_kernel<<<B * C2, 256, 0, stream>>>(y, s0);
    se_fc_kernel<<<B, 256, 0, stream>>>(s0, fc1_w, fc2_w, att);
    pack_kernel<<<C2, 256, 0, stream>>>(conv_w, conv_b, conv1_w, conv1_b,
                                        bn_g, bn_b, bn_m, bn_v, att,
                                        w0b, w1p, w1y, sA, sB0, sB1);
    dwcov_kernel<<<B * C, 256, 0, stream>>>(x, dw_w, dw_b, cov);
    // N = 8*784 = 6272 = 98 x 64 tiles; 8 o-tiles -> 784 blocks
    mfma_gemm<0, 1024><<<dim3(98 * 8, 1, 1), 256, 0, stream>>>(w0b, cov, nullptr, sA, sB0, x2s);
    mfma_gemm<1, 1536><<<dim3(98 * 8, 1, 1), 256, 0, stream>>>(w1p, x2s, x, sA, sB0, P);
    // N = 3136 = 49 x 64 tiles; 8 o-tiles; z = batch -> 3136 blocks
    mfma_gemm<2, 512><<<dim3(49 * 8, 1, 8), 256, 0, stream>>>(w1y, y, P, sA, sB1, out);
}

// Round 7
// 354.338 us; speedup vs baseline: 1.4607x; 1.1887x over previous
//
#include <hip/hip_runtime.h>
#include <math.h>

#define EPSV 1e-5f
#define B 8
#define C 1024
#define C2 512
#define RK 73
#define HW 784      // 28*28
#define QW 3136     // 56*56

typedef __attribute__((ext_vector_type(8))) short bf16x8;
typedef __attribute__((ext_vector_type(4))) float f32x4;

__device__ __forceinline__ unsigned short f2bf(float f) {
    unsigned u = __float_as_uint(f);
    return (unsigned short)((u + 0x7fffu + ((u >> 16) & 1u)) >> 16);
}
__device__ __forceinline__ float ld_f(const float* p) { return *p; }
__device__ __forceinline__ float ld_f(const unsigned short* p) {
    return __uint_as_float(((unsigned)*p) << 16);
}

// ---------- kernel 1: global average pool over y -> s0 ----------
__global__ void gap_kernel(const float* __restrict__ y, float* __restrict__ s0) {
    int bc = blockIdx.x;
    const float* p = y + (size_t)bc * QW;
    float sum = 0.f;
    for (int i = threadIdx.x; i < QW; i += 256) sum += p[i];
    for (int off = 32; off > 0; off >>= 1) sum += __shfl_down(sum, off, 64);
    __shared__ float red[4];
    if ((threadIdx.x & 63) == 0) red[threadIdx.x >> 6] = sum;
    __syncthreads();
    if (threadIdx.x == 0)
        s0[bc] = (red[0] + red[1] + red[2] + red[3]) * (1.0f / QW);
}

// ---------- kernel 2: SE FC layers ----------
__global__ void se_fc_kernel(const float* __restrict__ s0,
                             const float* __restrict__ fc1_w,
                             const float* __restrict__ fc2_w,
                             float* __restrict__ att) {
    int b = blockIdx.x;
    __shared__ float sv[C2];
    __shared__ float hv[RK];
    for (int i = threadIdx.x; i < C2; i += 256) sv[i] = s0[b * C2 + i];
    __syncthreads();
    if (threadIdx.x < RK) {
        float acc = 0.f;
        const float* wr = fc1_w + threadIdx.x * C2;
        for (int k = 0; k < C2; ++k) acc += wr[k] * sv[k];
        hv[threadIdx.x] = fmaxf(acc, 0.f);
    }
    __syncthreads();
    for (int o = threadIdx.x; o < C2; o += 256) {
        float acc = 0.f;
        const float* wr = fc2_w + o * RK;
        for (int j = 0; j < RK; ++j) acc += wr[j] * hv[j];
        att[b * C2 + o] = 1.f / (1.f + expf(-acc));
    }
}

// ---------- kernel 3: depthwise 3x3 conv + row-centered cov -> bf16 ----------
__global__ void dwcov_kernel(const float* __restrict__ x,
                             const float* __restrict__ dw_w,
                             const float* __restrict__ dw_b,
                             unsigned short* __restrict__ cov) {
    int bc = blockIdx.x;
    int c = bc & (C - 1);
    __shared__ float xs[HW];
    __shared__ float x1[HW];
    __shared__ float rm[28];
    const float* px = x + (size_t)bc * HW;
    for (int i = threadIdx.x; i < HW; i += 256) xs[i] = px[i];
    float wk[9];
#pragma unroll
    for (int j = 0; j < 9; ++j) wk[j] = dw_w[c * 9 + j];
    float bias = dw_b[c];
    __syncthreads();
    for (int p = threadIdx.x; p < HW; p += 256) {
        int h = p / 28, w = p - h * 28;
        float acc = bias;
#pragma unroll
        for (int dh = 0; dh < 3; ++dh) {
            int hh = h + dh - 1;
            if (hh < 0 || hh >= 28) continue;
#pragma unroll
            for (int dw = 0; dw < 3; ++dw) {
                int ww = w + dw - 1;
                if (ww < 0 || ww >= 28) continue;
                acc += xs[hh * 28 + ww] * wk[dh * 3 + dw];
            }
        }
        x1[p] = acc;
    }
    __syncthreads();
    if (threadIdx.x < 28) {
        float s = 0.f;
        for (int w = 0; w < 28; ++w) s += x1[threadIdx.x * 28 + w];
        rm[threadIdx.x] = s * (1.f / 28.f);
    }
    __syncthreads();
    unsigned short* pc = cov + (size_t)bc * HW;
    for (int p = threadIdx.x; p < HW; p += 256) {
        int h = p / 28, g = p - h * 28;
        float mh = rm[h], mg = rm[g];
        float acc = 0.f;
        for (int w = 0; w < 28; ++w)
            acc += (x1[h * 28 + w] - mh) * (x1[g * 28 + w] - mg);
        pc[p] = f2bf(acc * (1.f / 27.f));
    }
}

// ---------- pack weights bf16; fold att into per-batch w1y; fold bias+bn ----------
__global__ void pack_w(const float* __restrict__ conv_w, const float* __restrict__ conv_b,
                       const float* __restrict__ conv1_w, const float* __restrict__ conv1_b,
                       const float* __restrict__ bn_g, const float* __restrict__ bn_b,
                       const float* __restrict__ bn_m, const float* __restrict__ bn_v,
                       const float* __restrict__ att,
                       unsigned short* __restrict__ w0b, unsigned short* __restrict__ w1y,
                       unsigned short* __restrict__ w1pT,
                       float* __restrict__ sA, float* __restrict__ sB0, float* __restrict__ sB1) {
    int o = blockIdx.x, t = threadIdx.x;
    for (int i = t; i < C; i += 256) w0b[(size_t)o * C + i] = f2bf(conv_w[(size_t)o * C + i]);
    for (int i = t; i < 1536; i += 256) w1pT[(size_t)o * 1536 + i] = f2bf(conv1_w[(size_t)o * 2048 + 512 + i]);
#pragma unroll
    for (int b = 0; b < B; ++b)
        for (int c = t; c < C2; c += 256)
            w1y[((size_t)b * C2 + o) * C2 + c] = f2bf(conv1_w[(size_t)o * 2048 + c] * att[b * C2 + c]);
    if (t == 0) {
        float sc = rsqrtf(bn_v[o] + EPSV) * bn_g[o];
        float bi = bn_b[o] - bn_m[o] * sc;
        sA[o] = sc;
        sB0[o] = conv_b[o] * sc + bi;
        sB1[o] = conv1_b[o] * sc + bi;
    }
}

// ---------- tiled transpose+convert: src[b][rows][cols] -> dst[(b,col)][dpitch]+doff ----------
__global__ __launch_bounds__(256)
void transpose_pass(const float* __restrict__ src, unsigned short* __restrict__ dst,
                    int rows, int cols, int dpitch, int doff) {
    int b = blockIdx.z;
    int c0 = blockIdx.y * 64, p0 = blockIdx.x * 64;
    __shared__ float ts[64][65];
    int tid = threadIdx.x;
    int pl = tid & 63, r0 = tid >> 6;
    const float* sb = src + ((size_t)b * rows + c0) * cols + p0;
    if (p0 + pl < cols) {
#pragma unroll
        for (int j = 0; j < 16; ++j) {
            int cl = r0 + j * 4;
            ts[cl][pl] = sb[(size_t)cl * cols + pl];
        }
    }
    __syncthreads();
    int cl = tid & 63;
#pragma unroll
    for (int j = 0; j < 16; ++j) {
        int pl2 = r0 + j * 4;
        if (p0 + pl2 < cols)
            dst[((size_t)b * cols + p0 + pl2) * dpitch + doff + c0 + cl] = f2bf(ts[cl][pl2]);
    }
}

// ---------- MFMA GEMM: 64o x 64n, BK=32, VGPR double-buffered staging ----------
// MODE 0: A=w0b, B=cov_bf bf16 strided (stride HW), N=6272(b,p); epi bn+sigmoid -> BcatT cols 0..511
// MODE 1: A=w1pT, B=BcatT contiguous rows (pitch 1536), N=6272; epi f2bf -> Pb [b][o][784]
// MODE 2: A=w1y[b], B=y f32 strided (stride QW), N=3136 (z=b); epi (acc+up(Pb))*bn relu -> out
template<int MODE, int K>
__global__ __launch_bounds__(256)
void mfma_gemm(const unsigned short* __restrict__ wpk,
               const void* __restrict__ bsrc_v,
               const unsigned short* __restrict__ Pb,
               const float* __restrict__ sA, const float* __restrict__ sB,
               void* __restrict__ outv) {
    constexpr int NIT = K / 32;
    int bx = blockIdx.x;
    int o0 = (bx & 7) * 64;          // o-fastest for B-slice L2 reuse
    int n0 = (bx >> 3) * 64;
    int b = blockIdx.z;
    union SM {
        struct { __align__(16) unsigned short Wt[2][2560]; __align__(16) unsigned short At[2][2560]; } s;
        float pt[(MODE == 2) ? 64 * 84 : 4];
    };
    __shared__ SM sm;
    int tid = threadIdx.x;
    int lane = tid & 63, wv = tid >> 6;
    int ln = lane & 15, quad = lane >> 4;
    int o_w = (wv >> 1) * 32, q_w = (wv & 1) * 32;
    int swr = tid >> 2, swk = (tid & 3) * 8;   // 16B staging: row, k-off
    int s_gq = tid & 63, s_gk8 = tid >> 6;     // strided staging: n, k-octet
    int qg = n0 + s_gq;
    const unsigned short* wp = (MODE == 2) ? wpk + (size_t)b * C2 * C2 : wpk;
    const unsigned short* wg = wp + (size_t)(o0 + swr) * K + swk;
    // B pointers
    const unsigned short* bg_s = nullptr;  // MODE0 strided bf16
    const unsigned short* bg_c = nullptr;  // MODE1 contiguous
    const float* bg_f = nullptr;           // MODE2 strided f32
    if (MODE == 0) {
        int bq = qg / HW, pp = qg - bq * HW;
        bg_s = (const unsigned short*)bsrc_v + ((size_t)bq * C + s_gk8 * 8) * HW + pp;
    } else if (MODE == 1) {
        bg_c = (const unsigned short*)bsrc_v + (size_t)(n0 + swr) * K + swk;
    } else {
        bg_f = (const float*)bsrc_v + ((size_t)b * C2 + s_gk8 * 8) * QW + qg;
    }

    // prologue: chunk 0 -> LDS[0]
    {
        float4 wv4 = *(const float4*)wg;
        *(float4*)&sm.s.Wt[0][swr * 40 + swk] = wv4;
        unsigned short pk[8];
        if (MODE == 0) {
#pragma unroll
            for (int j = 0; j < 8; ++j) pk[j] = bg_s[(size_t)j * HW];
            *(float4*)&sm.s.At[0][s_gq * 40 + s_gk8 * 8] = *(float4*)pk;
        } else if (MODE == 1) {
            *(float4*)&sm.s.At[0][swr * 40 + swk] = *(const float4*)bg_c;
        } else {
#pragma unroll
            for (int j = 0; j < 8; ++j) pk[j] = f2bf(bg_f[(size_t)j * QW]);
            *(float4*)&sm.s.At[0][s_gq * 40 + s_gk8 * 8] = *(float4*)pk;
        }
    }
    __syncthreads();

    f32x4 acc[2][2] = {};
    for (int i = 0; i < NIT; ++i) {
        int cur = i & 1;
        float4 wn;
        unsigned short bn[8];
        if (i + 1 < NIT) {               // prefetch next chunk into VGPRs
            wn = *(const float4*)(wg + (size_t)(i + 1) * 32);
            if (MODE == 0) {
                const unsigned short* s = bg_s + (size_t)(i + 1) * 32 * HW;
#pragma unroll
                for (int j = 0; j < 8; ++j) bn[j] = s[(size_t)j * HW];
            } else if (MODE == 1) {
                *(float4*)bn = *(const float4*)(bg_c + (size_t)(i + 1) * 32);
            } else {
                const float* s = bg_f + (size_t)(i + 1) * 32 * QW;
#pragma unroll
                for (int j = 0; j < 8; ++j) bn[j] = f2bf(s[(size_t)j * QW]);
            }
        }
        bf16x8 af[2], bfr[2];
#pragma unroll
        for (int mt = 0; mt < 2; ++mt)
            af[mt] = *(const bf16x8*)&sm.s.Wt[cur][(o_w + mt * 16 + ln) * 40 + quad * 8];
#pragma unroll
        for (int nt = 0; nt < 2; ++nt)
            bfr[nt] = *(const bf16x8*)&sm.s.At[cur][(q_w + nt * 16 + ln) * 40 + quad * 8];
#pragma unroll
        for (int mt = 0; mt < 2; ++mt)
#pragma unroll
            for (int nt = 0; nt < 2; ++nt)
                acc[mt][nt] = __builtin_amdgcn_mfma_f32_16x16x32_bf16(af[mt], bfr[nt], acc[mt][nt], 0, 0, 0);
        if (i + 1 < NIT) {
            int nxt = cur ^ 1;
            *(float4*)&sm.s.Wt[nxt][swr * 40 + swk] = wn;
            if (MODE == 1) *(float4*)&sm.s.At[nxt][swr * 40 + swk] = *(float4*)bn;
            else           *(float4*)&sm.s.At[nxt][s_gq * 40 + s_gk8 * 8] = *(float4*)bn;
            __syncthreads();
        }
    }

    // ---- epilogue; D: row = quad*4+reg, col = ln ----
    if (MODE == 2) {
        float* outp = (float*)outv;
        __syncthreads();
        int h0 = n0 / 56;
        int hmin = (h0 & 1) ? (h0 >> 1) : max(0, (h0 >> 1) - 1);
        for (int e = tid; e < 64 * 84; e += 256) {
            int o_l = e / 84, rem = e - o_l * 84;
            int s = rem / 28, w = rem - s * 28;
            int row = min(hmin + s, 27);
            sm.pt[e] = ld_f(&Pb[((size_t)b * C2 + o0 + o_l) * HW + row * 28 + w]);
        }
        __syncthreads();
#pragma unroll
        for (int nt = 0; nt < 2; ++nt) {
            int q = n0 + q_w + nt * 16 + ln;
            int hq = q / 56, wq = q - hq * 56;
            int hm = hq >> 1, wm = wq >> 1;
            int hn = (hq & 1) ? min(hm + 1, 27) : max(hm - 1, 0);
            int wn_ = (wq & 1) ? min(wm + 1, 27) : max(wm - 1, 0);
            int rm_ = (hm - hmin) * 28, rn_ = (hn - hmin) * 28;
#pragma unroll
            for (int mt = 0; mt < 2; ++mt)
#pragma unroll
                for (int reg = 0; reg < 4; ++reg) {
                    int ol = o_w + mt * 16 + quad * 4 + reg;
                    int o = o0 + ol;
                    const float* Pt = &sm.pt[ol * 84];
                    float up = 0.5625f * Pt[rm_ + wm] + 0.1875f * (Pt[rm_ + wn_] + Pt[rn_ + wm])
                             + 0.0625f * Pt[rn_ + wn_];
                    float v = (acc[mt][nt][reg] + up) * sA[o] + sB[o];
                    outp[((size_t)b * C2 + o) * QW + q] = fmaxf(v, 0.f);
                }
        }
    } else if (MODE == 0) {
        unsigned short* outp = (unsigned short*)outv;   // BcatT, pitch 1536, cols 0..511
#pragma unroll
        for (int nt = 0; nt < 2; ++nt) {
            int n = n0 + q_w + nt * 16 + ln;
#pragma unroll
            for (int mt = 0; mt < 2; ++mt) {
                int ob = o0 + o_w + mt * 16 + quad * 4;
                unsigned short pk[4];
#pragma unroll
                for (int reg = 0; reg < 4; ++reg) {
                    int o = ob + reg;
                    float v = acc[mt][nt][reg] * sA[o] + sB[o];
                    pk[reg] = f2bf(1.f / (1.f + expf(-v)));
                }
                *(uint2*)&outp[(size_t)n * 1536 + ob] = *(uint2*)pk;
            }
        }
    } else {
        unsigned short* outp = (unsigned short*)outv;   // Pb [b][o][784] bf16
#pragma unroll
        for (int nt = 0; nt < 2; ++nt) {
            int n = n0 + q_w + nt * 16 + ln;
            int be = n / HW, pe = n - be * HW;
#pragma unroll
            for (int mt = 0; mt < 2; ++mt)
#pragma unroll
                for (int reg = 0; reg < 4; ++reg) {
                    int o = o0 + o_w + mt * 16 + quad * 4 + reg;
                    outp[((size_t)be * C2 + o) * HW + pe] = f2bf(acc[mt][nt][reg]);
                }
        }
    }
}

extern "C" void kernel_launch(void* const* d_in, const int* in_sizes, int n_in,
                              void* d_out, int out_size, void* d_ws, size_t ws_size,
                              hipStream_t stream) {
    const float* y       = (const float*)d_in[0];
    const float* x       = (const float*)d_in[1];
    const float* fc1_w   = (const float*)d_in[2];
    const float* fc2_w   = (const float*)d_in[3];
    const float* conv_w  = (const float*)d_in[4];
    const float* conv_b  = (const float*)d_in[5];
    const float* conv1_w = (const float*)d_in[6];
    const float* conv1_b = (const float*)d_in[7];
    const float* bn_g    = (const float*)d_in[8];
    const float* bn_b    = (const float*)d_in[9];
    const float* bn_m    = (const float*)d_in[10];
    const float* bn_v    = (const float*)d_in[11];
    const float* dw_w    = (const float*)d_in[12];
    const float* dw_b    = (const float*)d_in[13];
    float* out = (float*)d_out;

    // ---- workspace carve: NO aliasing; total = 45,389,824 B (== Round-2-proven extent) ----
    float* ws  = (float*)d_ws;
    float* s0  = ws;                 // 4096
    float* att = ws + 4096;          // 4096
    float* sA  = ws + 8192;          // 512
    float* sB0 = ws + 8704;          // 512
    float* sB1 = ws + 9216;          // 512 -> header ends at float 9728 (byte 38912, 16B-aligned)
    unsigned short* w0b    = (unsigned short*)(ws + 9728);   // 512*1024 sh
    unsigned short* w1y    = w0b + (size_t)C2 * C;           // 8*512*512 sh
    unsigned short* w1pT   = w1y + (size_t)B * C2 * C2;      // 512*1536 sh
    unsigned short* cov_bf = w1pT + (size_t)C2 * 1536;       // 8*1024*784 sh
    unsigned short* BcatT  = cov_bf + (size_t)B * C * HW;    // 6272*1536 sh
    unsigned short* Pb     = BcatT + (size_t)B * HW * 1536;  // 8*512*784 sh

    gap_kernel<<<B * C2, 256, 0, stream>>>(y, s0);
    se_fc_kernel<<<B, 256, 0, stream>>>(s0, fc1_w, fc2_w, att);
    pack_w<<<C2, 256, 0, stream>>>(conv_w, conv_b, conv1_w, conv1_b,
                                   bn_g, bn_b, bn_m, bn_v, att,
                                   w0b, w1y, w1pT, sA, sB0, sB1);
    dwcov_kernel<<<B * C, 256, 0, stream>>>(x, dw_w, dw_b, cov_bf);
    // xT: x[b][c][p] -> BcatT[(b,p)][512+c]
    transpose_pass<<<dim3(13, 16, B), 256, 0, stream>>>(x, BcatT, C, HW, 1536, 512);
    // M0: x2s = sigmoid(bn(conv(cov))) -> BcatT cols 0..511
    mfma_gemm<0, 1024><<<dim3(98 * 8), 256, 0, stream>>>(w0b, cov_bf, nullptr, sA, sB0, BcatT);
    // M1: Pb = w1[:,512:]·[x2s|x]  (bf16)
    mfma_gemm<1, 1536><<<dim3(98 * 8), 256, 0, stream>>>(w1pT, BcatT, nullptr, sA, sB0, Pb);
    // M2: out = relu(bn(w1y[b]·y + up(Pb)))
    mfma_gemm<2, 512><<<dim3(49 * 8, 1, B), 256, 0, stream>>>(w1y, y, Pb, sA, sB1, out);
}